// Round 4
// baseline (289.570 us; speedup 1.0000x reference)
//
#include <hip/hip_runtime.h>
#include <math.h>

// SIFA fused, MFMA v2.1 (fix cvt_pkrtz type).
// z[b,o,oh,ow] = sum_{c,j} conv_w[o,c,j] * gate(y[b,c*9+j,oh,ow]); per block a
// 128oup x 64px GEMM, K = 64 chans * 16 (9 real j + 7 zero-pad), f16 MFMA.
// u recomputed on the fly; per-(b,c) stats from k_stats/k_gate.
// v2: wave-uniform channel (scalar dwconv weights), A-frags direct from global,
// double-buffered halo, exp2/rcp gate, 128x64 tile for occupancy.

#define EPSF 1e-5f
typedef _Float16 v8h __attribute__((ext_vector_type(8)));
typedef __fp16 fp16x2 __attribute__((ext_vector_type(2)));   // cvt_pkrtz native type
typedef float v4f __attribute__((ext_vector_type(4)));

static constexpr int C_ = 64, HW_ = 16384, W_ = 128;

// ws float offsets
static constexpr int WS_WFOLD = 0;      // 5184: [c][j][k] folded depthwise weights
static constexpr int WS_SHIFT = 5184;   // 576
static constexpr int WS_BIAS  = 5760;   // 128
static constexpr int WS_GATE  = 5888;   // 512*4 {wa*cgate, 1-wa, -log2e*a_sp, -log2e*b_sp}
static constexpr int WS_PART  = 7936;   // 2048*2 partial sums
static constexpr int WS_WH    = 12032;  // 131072 f16: Wh[oup][c*16+j] (j<9), else 0

__device__ __forceinline__ float sigmf(float v) { return 1.f / (1.f + __expf(-v)); }

__global__ __launch_bounds__(256) void k_fold(
    const float* __restrict__ gen_w,
    const float* __restrict__ gg, const float* __restrict__ gb,
    const float* __restrict__ gm, const float* __restrict__ gv,
    const float* __restrict__ conv_w,
    const float* __restrict__ cg, const float* __restrict__ cb,
    const float* __restrict__ cm, const float* __restrict__ cv,
    float* __restrict__ ws)
{
    int idx = blockIdx.x * 256 + threadIdx.x;
    _Float16* Whp = (_Float16*)(ws + WS_WH);
    if (idx < 131072) {
        int oup = idx >> 10, kk = idx & 1023, c = kk >> 4, j = kk & 15;
        float s = cg[oup] * rsqrtf(cv[oup] + EPSF);
        float v = (j < 9) ? conv_w[(oup * C_ + c) * 9 + j] * s : 0.f;
        Whp[idx] = (_Float16)v;
    } else if (idx < 136256) {
        int i = idx - 131072; int ce = i / 9;
        float s = gg[ce] * rsqrtf(gv[ce] + EPSF);
        ws[WS_WFOLD + i] = gen_w[i] * s;
    } else if (idx < 136832) {
        int ce = idx - 136256;
        float s = gg[ce] * rsqrtf(gv[ce] + EPSF);
        ws[WS_SHIFT + ce] = gb[ce] - gm[ce] * s;
    } else if (idx < 136960) {
        int oup = idx - 136832;
        float s = cg[oup] * rsqrtf(cv[oup] + EPSF);
        ws[WS_BIAS + oup] = cb[oup] - cm[oup] * s;
    }
}

// 2048 blocks: (b, c, quarter). LDS-staged slab, partials to ws.
__global__ __launch_bounds__(256) void k_stats(
    const float* __restrict__ x, const float* __restrict__ ws,
    float* __restrict__ part)
{
    __shared__ float xs[34 * 132];
    __shared__ float r1[256], r2[256];
    int bid = blockIdx.x; int b = bid >> 8; int c = (bid >> 2) & 63; int q = bid & 3;
    int t = threadIdx.x;
    const float* xp = x + (size_t)(b * C_ + c) * HW_;
    for (int i = t; i < 4420; i += 256) {
        int r = i / 130, cc = i - r * 130;
        int yy = q * 32 + r - 1, xx = cc - 1;
        float v = 0.f;
        if (yy >= 0 && yy < 128 && xx >= 0 && xx < 128) v = xp[yy * 128 + xx];
        xs[r * 132 + cc] = v;
    }
    __syncthreads();
    const float* wf = ws + WS_WFOLD + c * 81;   // block-uniform -> scalar loads
    const float* sh = ws + WS_SHIFT + c * 9;
    float s1 = 0.f, s2 = 0.f;
    for (int i = 0; i < 16; ++i) {
        int id = i * 256 + t; int row = id >> 7, col = id & 127;
        float nb[9];
#pragma unroll
        for (int dy = 0; dy < 3; ++dy)
#pragma unroll
            for (int dx = 0; dx < 3; ++dx) nb[dy * 3 + dx] = xs[(row + dy) * 132 + col + dx];
        float uv[9];
#pragma unroll
        for (int j = 0; j < 9; ++j) uv[j] = sh[j];
#pragma unroll
        for (int k = 0; k < 9; ++k) {
            float xv = nb[k];
#pragma unroll
            for (int j = 0; j < 9; ++j) uv[j] = fmaf(wf[j * 9 + k], xv, uv[j]);
        }
#pragma unroll
        for (int j = 0; j < 9; ++j) {
            float v = fmaxf(uv[j], 0.f);
            s1 += v; s2 = fmaf(v, v, s2);
        }
    }
    r1[t] = s1; r2[t] = s2;
    __syncthreads();
    for (int s = 128; s > 0; s >>= 1) {
        if (t < s) { r1[t] += r1[t + s]; r2[t] += r2[t + s]; }
        __syncthreads();
    }
    if (t == 0) { part[bid * 2] = r1[0]; part[bid * 2 + 1] = r2[0]; }
}

__global__ __launch_bounds__(256) void k_gate(
    const float* __restrict__ part,
    const float* __restrict__ cwt, const float* __restrict__ cbs,
    const float* __restrict__ swt, const float* __restrict__ sbs,
    const float* __restrict__ gnw, const float* __restrict__ gnb,
    const float* __restrict__ wadd, float4* __restrict__ gate)
{
    int i = blockIdx.x * 256 + threadIdx.x;
    if (i >= 512) return;
    int b = i >> 6, c = i & 63;
    float s1 = 0.f, s2 = 0.f;
    for (int q = 0; q < 4; ++q) {
        int pi = (b * 256 + c * 4 + q) * 2;
        s1 += part[pi]; s2 += part[pi + 1];
    }
    const float N = 9.f * 16384.f;
    float mean = s1 / N;
    float var = s2 / N - mean * mean;
    float inv = rsqrtf(var + EPSF);
    int cgi = c & 7;
    float wa = wadd[0];
    float cgt = sigmf(cwt[cgi] * mean + cbs[cgi]);
    const float NL2E = -1.44269504f;   // fold -log2(e): sigm(t)=rcp(1+exp2(-t*log2e))
    float4 o;
    o.x = wa * cgt;
    o.y = 1.f - wa;
    o.z = NL2E * (swt[cgi] * gnw[cgi] * inv);
    o.w = NL2E * (swt[cgi] * (gnb[cgi] - mean * inv * gnw[cgi]) + sbs[cgi]);
    gate[i] = o;
}

// 2048 blocks: (b, 8x8 pixel tile). 128oup x 64px f32 acc via f16 MFMA.
__global__ __launch_bounds__(256) void k_main(
    const float* __restrict__ x, const float* __restrict__ ws,
    float* __restrict__ out)
{
    __shared__ _Float16 u_s[64 * 64];   // row=pixel, 64 f16 K-chunk, XOR-swizzled
    __shared__ float xs[2][4 * 120];    // dbuf: 4 chans x (10 rows x stride 12)
    __shared__ float bias_s[128];

    int t = threadIdx.x;
    int bid = blockIdx.x;
    int b = bid >> 8, tile = bid & 255;
    int oh0 = (tile >> 4) << 3, ow0 = (tile & 15) << 3;
    if (t < 128) bias_s[t] = ws[WS_BIAS + t];

    const float* xb = x + (size_t)b * C_ * HW_;
    const _Float16* Wh = (const _Float16*)(ws + WS_WH);

    int w = __builtin_amdgcn_readfirstlane(t >> 6);   // honest: uniform per wave
    int lane = t & 63, quad = lane >> 4, l15 = lane & 15;
    int py = lane >> 3, px = lane & 7;                // u-phase pixel (1/lane)

    v4f acc[4][2];
#pragma unroll
    for (int a = 0; a < 4; ++a)
#pragma unroll
        for (int bb = 0; bb < 2; ++bb) acc[a][bb] = (v4f)0.f;

    // ---- stage halo for it=0: wave w stages chan w (uniform row base)
    {
        const float* xc = xb + (size_t)w * HW_;
#pragma unroll
        for (int i = 0; i < 2; ++i) {
            int item = lane + i * 64;
            if (item < 100) {
                int r = item / 10, cl = item - r * 10;
                int yy = oh0 + r - 1, xx = ow0 + cl - 1;
                float v = 0.f;
                if (yy >= 0 && yy < 128 && xx >= 0 && xx < 128) v = xc[yy * 128 + xx];
                xs[0][w * 120 + r * 12 + cl] = v;
            }
        }
    }
    __syncthreads();

    int buf = 0;
    for (int it = 0; it < 16; ++it) {
        int c = it * 4 + w;                            // wave-uniform channel
        const float* wfp = ws + WS_WFOLD + c * 81;     // scalar s_load path
        const float* shp = ws + WS_SHIFT + c * 9;
        float4 g4 = *(const float4*)(ws + WS_GATE + (((b << 6) + c) << 2));

        // ---- u-phase: 1 pixel per lane, channel c
        float nb[9];
        const float* xw = &xs[buf][w * 120];
#pragma unroll
        for (int dy = 0; dy < 3; ++dy)
#pragma unroll
            for (int dx = 0; dx < 3; ++dx)
                nb[dy * 3 + dx] = xw[(py + dy) * 12 + px + dx];
        float uv[9];
#pragma unroll
        for (int j = 0; j < 9; ++j) uv[j] = shp[j];
#pragma unroll
        for (int k = 0; k < 9; ++k) {
            float xv = nb[k];
#pragma unroll
            for (int j = 0; j < 9; ++j) uv[j] = fmaf(wfp[j * 9 + k], xv, uv[j]);
        }
        float ug[9];
#pragma unroll
        for (int j = 0; j < 9; ++j) {
            float v = fmaxf(uv[j], 0.f);
            float e = __builtin_amdgcn_exp2f(fmaf(g4.z, v, g4.w));
            float g2 = fmaf(g4.y, __builtin_amdgcn_rcpf(1.f + e), g4.x);
            ug[j] = v * g2;
        }
        union { fp16x2 p[8]; float4 f[2]; } pk;
        pk.p[0] = __builtin_amdgcn_cvt_pkrtz(ug[0], ug[1]);
        pk.p[1] = __builtin_amdgcn_cvt_pkrtz(ug[2], ug[3]);
        pk.p[2] = __builtin_amdgcn_cvt_pkrtz(ug[4], ug[5]);
        pk.p[3] = __builtin_amdgcn_cvt_pkrtz(ug[6], ug[7]);
        pk.p[4] = __builtin_amdgcn_cvt_pkrtz(ug[8], 0.f);
        pk.p[5] = __builtin_amdgcn_cvt_pkrtz(0.f, 0.f);
        pk.p[6] = __builtin_amdgcn_cvt_pkrtz(0.f, 0.f);
        pk.p[7] = __builtin_amdgcn_cvt_pkrtz(0.f, 0.f);
        {
            int g0 = 2 * w;
            *(float4*)&u_s[lane * 64 + ((g0 ^ (lane & 7)) << 3)] = pk.f[0];
            *(float4*)&u_s[lane * 64 + (((g0 + 1) ^ (lane & 7)) << 3)] = pk.f[1];
        }

        // ---- A-frags straight from global (L2-hot), issued before the barrier
        v8h A[2][4];
#pragma unroll
        for (int ks = 0; ks < 2; ++ks)
#pragma unroll
            for (int a = 0; a < 4; ++a) {
                int row = ((w & 1) << 6) + (a << 4) + l15;
                A[ks][a] = *(const v8h*)(Wh + (size_t)row * 1024 + it * 64 + ((ks * 4 + quad) << 3));
            }
        __syncthreads();

        // ---- stage halo for it+1 during MFMA phase (overlaps compute)
        if (it < 15) {
            int cn = (it + 1) * 4 + w;
            const float* xc = xb + (size_t)cn * HW_;
#pragma unroll
            for (int i = 0; i < 2; ++i) {
                int item = lane + i * 64;
                if (item < 100) {
                    int r = item / 10, cl = item - r * 10;
                    int yy = oh0 + r - 1, xx = ow0 + cl - 1;
                    float v = 0.f;
                    if (yy >= 0 && yy < 128 && xx >= 0 && xx < 128) v = xc[yy * 128 + xx];
                    xs[buf ^ 1][w * 120 + r * 12 + cl] = v;
                }
            }
        }

        // ---- MFMA: wave w owns oups [(w&1)*64,+64) x px [(w>>1)*32,+32)
#pragma unroll
        for (int ks = 0; ks < 2; ++ks) {
            int kb = ks * 4 + quad;
            v8h Bf[2];
#pragma unroll
            for (int bb = 0; bb < 2; ++bb) {
                int row = ((w >> 1) << 5) + (bb << 4) + l15;
                Bf[bb] = *(const v8h*)&u_s[row * 64 + ((kb ^ (row & 7)) << 3)];
            }
#pragma unroll
            for (int a = 0; a < 4; ++a)
#pragma unroll
                for (int bb = 0; bb < 2; ++bb)
                    acc[a][bb] = __builtin_amdgcn_mfma_f32_16x16x32_f16(A[ks][a], Bf[bb], acc[a][bb], 0, 0, 0);
        }
        __syncthreads();
        buf ^= 1;
    }

    // ---- epilogue: bias + SiLU; C/D layout col=lane&15(px), row=quad*4+reg(oup)
    size_t ob = (size_t)b * 128 * HW_;
#pragma unroll
    for (int a = 0; a < 4; ++a) {
#pragma unroll
        for (int r = 0; r < 4; ++r) {
            int oup = ((w & 1) << 6) + (a << 4) + (quad << 2) + r;
            float bo = bias_s[oup];
#pragma unroll
            for (int bb = 0; bb < 2; ++bb) {
                int p2 = ((w >> 1) << 5) + (bb << 4) + l15;
                int py2 = p2 >> 3, px2 = p2 & 7;
                float z = acc[a][bb][r] + bo;
                out[ob + (size_t)oup * HW_ + (oh0 + py2) * W_ + ow0 + px2] = z * sigmf(z);
            }
        }
    }
}

extern "C" void kernel_launch(void* const* d_in, const int* in_sizes, int n_in,
                              void* d_out, int out_size, void* d_ws, size_t ws_size,
                              hipStream_t stream)
{
    const float* x      = (const float*)d_in[0];
    const float* gen_w  = (const float*)d_in[1];
    const float* gg     = (const float*)d_in[2];
    const float* gb     = (const float*)d_in[3];
    const float* gm     = (const float*)d_in[4];
    const float* gv     = (const float*)d_in[5];
    const float* gnw    = (const float*)d_in[6];
    const float* gnb    = (const float*)d_in[7];
    const float* cwt    = (const float*)d_in[8];
    const float* cbs    = (const float*)d_in[9];
    const float* swt    = (const float*)d_in[10];
    const float* sbs    = (const float*)d_in[11];
    const float* wadd   = (const float*)d_in[12];
    const float* conv_w = (const float*)d_in[13];
    const float* cg2    = (const float*)d_in[14];
    const float* cb2    = (const float*)d_in[15];
    const float* cm2    = (const float*)d_in[16];
    const float* cv2    = (const float*)d_in[17];
    float* ws  = (float*)d_ws;
    float* out = (float*)d_out;

    k_fold<<<535, 256, 0, stream>>>(gen_w, gg, gb, gm, gv, conv_w, cg2, cb2, cm2, cv2, ws);
    k_stats<<<2048, 256, 0, stream>>>(x, ws, ws + WS_PART);
    k_gate<<<2, 256, 0, stream>>>(ws + WS_PART, cwt, cbs, swt, sbs, gnw, gnb, wadd,
                                  (float4*)(ws + WS_GATE));
    k_main<<<2048, 256, 0, stream>>>(x, ws, out);
}

// Round 5
// 252.590 us; speedup vs baseline: 1.1464x; 1.1464x over previous
//
#include <hip/hip_runtime.h>
#include <math.h>

// SIFA fused, MFMA v3.
// z[b,o,oh,ow] = sum_{c,j} conv_w[o,c,j] * gate(y[b,c*9+j,oh,ow]); per block a
// 128oup x 128px GEMM, K = 64 chans * 16 (9 real j + 7 zero-pad), f16 MFMA.
// v3 theory: R4's fully-unrolled j-loop kept 90 uniform scalars live ->
// SGPR-demotion -> per-lane VMEM storm (VALU 36%, MFMA 8.6%, stall-bound).
// Fix: k_stats keeps weights in VGPRs (compile-time indexed); k_main consumes
// weights j-pair-wise (<=18 live scalars, unroll-1 loop), gate applied per pair.

#define EPSF 1e-5f
typedef _Float16 v8h __attribute__((ext_vector_type(8)));
typedef __fp16 fp16x2 __attribute__((ext_vector_type(2)));   // cvt_pkrtz native type
typedef float v4f __attribute__((ext_vector_type(4)));

static constexpr int C_ = 64, HW_ = 16384, W_ = 128;

// ws float offsets
static constexpr int WS_WFOLD = 0;      // 5184: [c][j][k] folded depthwise weights
static constexpr int WS_SHIFT = 5184;   // 576
static constexpr int WS_BIAS  = 5760;   // 128
static constexpr int WS_GATE  = 5888;   // 512*4 {wa*cgate, 1-wa, -log2e*a_sp, -log2e*b_sp}
static constexpr int WS_PART  = 7936;   // 2048*2 partial sums
static constexpr int WS_WH    = 12032;  // 131072 f16: Wh[oup][c*16+j] (j<9), else 0

__device__ __forceinline__ float sigmf(float v) { return 1.f / (1.f + __expf(-v)); }

__global__ __launch_bounds__(256) void k_fold(
    const float* __restrict__ gen_w,
    const float* __restrict__ gg, const float* __restrict__ gb,
    const float* __restrict__ gm, const float* __restrict__ gv,
    const float* __restrict__ conv_w,
    const float* __restrict__ cg, const float* __restrict__ cb,
    const float* __restrict__ cm, const float* __restrict__ cv,
    float* __restrict__ ws)
{
    int idx = blockIdx.x * 256 + threadIdx.x;
    _Float16* Whp = (_Float16*)(ws + WS_WH);
    if (idx < 131072) {
        int oup = idx >> 10, kk = idx & 1023, c = kk >> 4, j = kk & 15;
        float s = cg[oup] * rsqrtf(cv[oup] + EPSF);
        float v = (j < 9) ? conv_w[(oup * C_ + c) * 9 + j] * s : 0.f;
        Whp[idx] = (_Float16)v;
    } else if (idx < 136256) {
        int i = idx - 131072; int ce = i / 9;
        float s = gg[ce] * rsqrtf(gv[ce] + EPSF);
        ws[WS_WFOLD + i] = gen_w[i] * s;
    } else if (idx < 136832) {
        int ce = idx - 136256;
        float s = gg[ce] * rsqrtf(gv[ce] + EPSF);
        ws[WS_SHIFT + ce] = gb[ce] - gm[ce] * s;
    } else if (idx < 136960) {
        int oup = idx - 136832;
        float s = cg[oup] * rsqrtf(cv[oup] + EPSF);
        ws[WS_BIAS + oup] = cb[oup] - cm[oup] * s;
    }
}

// 2048 blocks: (b, c, quarter). Weights copied LDS -> VGPR (compile-time
// indexed) so there is NO uniform-scalar pressure in the hot loop.
__global__ __launch_bounds__(256) void k_stats(
    const float* __restrict__ x, const float* __restrict__ ws,
    float* __restrict__ part)
{
    __shared__ float xs[34 * 132];
    __shared__ __align__(16) float wfl[84];
    __shared__ float shl[9];
    __shared__ float r1[256], r2[256];
    int bid = blockIdx.x; int b = bid >> 8; int c = (bid >> 2) & 63; int q = bid & 3;
    int t = threadIdx.x;
    const float* xp = x + (size_t)(b * C_ + c) * HW_;
    for (int i = t; i < 4420; i += 256) {
        int r = i / 130, cc = i - r * 130;
        int yy = q * 32 + r - 1, xx = cc - 1;
        float v = 0.f;
        if (yy >= 0 && yy < 128 && xx >= 0 && xx < 128) v = xp[yy * 128 + xx];
        xs[r * 132 + cc] = v;
    }
    if (t < 84) wfl[t] = ws[WS_WFOLD + c * 81 + ((t < 81) ? t : 80)];
    if (t >= 84 && t < 93) shl[t - 84] = ws[WS_SHIFT + c * 9 + (t - 84)];
    __syncthreads();

    float wv[84];
#pragma unroll
    for (int i = 0; i < 21; ++i) *(float4*)&wv[i * 4] = *(const float4*)&wfl[i * 4];
    float sh9[9];
#pragma unroll
    for (int i = 0; i < 9; ++i) sh9[i] = shl[i];

    float s1 = 0.f, s2 = 0.f;
    for (int i = 0; i < 16; ++i) {
        int id = i * 256 + t; int row = id >> 7, col = id & 127;
        float nb[9];
#pragma unroll
        for (int dy = 0; dy < 3; ++dy)
#pragma unroll
            for (int dx = 0; dx < 3; ++dx) nb[dy * 3 + dx] = xs[(row + dy) * 132 + col + dx];
        float uv[9];
#pragma unroll
        for (int j = 0; j < 9; ++j) uv[j] = sh9[j];
#pragma unroll
        for (int k = 0; k < 9; ++k) {
            float xv = nb[k];
#pragma unroll
            for (int j = 0; j < 9; ++j) uv[j] = fmaf(wv[j * 9 + k], xv, uv[j]);
        }
#pragma unroll
        for (int j = 0; j < 9; ++j) {
            float v = fmaxf(uv[j], 0.f);
            s1 += v; s2 = fmaf(v, v, s2);
        }
    }
    r1[t] = s1; r2[t] = s2;
    __syncthreads();
    for (int s = 128; s > 0; s >>= 1) {
        if (t < s) { r1[t] += r1[t + s]; r2[t] += r2[t + s]; }
        __syncthreads();
    }
    if (t == 0) { part[bid * 2] = r1[0]; part[bid * 2 + 1] = r2[0]; }
}

__global__ __launch_bounds__(256) void k_gate(
    const float* __restrict__ part,
    const float* __restrict__ cwt, const float* __restrict__ cbs,
    const float* __restrict__ swt, const float* __restrict__ sbs,
    const float* __restrict__ gnw, const float* __restrict__ gnb,
    const float* __restrict__ wadd, float4* __restrict__ gate)
{
    int i = blockIdx.x * 256 + threadIdx.x;
    if (i >= 512) return;
    int b = i >> 6, c = i & 63;
    float s1 = 0.f, s2 = 0.f;
    for (int q = 0; q < 4; ++q) {
        int pi = (b * 256 + c * 4 + q) * 2;
        s1 += part[pi]; s2 += part[pi + 1];
    }
    const float N = 9.f * 16384.f;
    float mean = s1 / N;
    float var = s2 / N - mean * mean;
    float inv = rsqrtf(var + EPSF);
    int cgi = c & 7;
    float wa = wadd[0];
    float cgt = sigmf(cwt[cgi] * mean + cbs[cgi]);
    const float NL2E = -1.44269504f;   // sigm(t)=rcp(1+exp2(-t*log2e))
    float4 o;
    o.x = wa * cgt;
    o.y = 1.f - wa;
    o.z = NL2E * (swt[cgi] * gnw[cgi] * inv);
    o.w = NL2E * (swt[cgi] * (gnb[cgi] - mean * inv * gnw[cgi]) + sbs[cgi]);
    gate[i] = o;
}

// 1024 blocks: (b, 8x16 px tile). 128oup x 128px f32 acc via f16 MFMA.
// wave <-> channel; weights j-pair-wise scalar (<=18 live); 2 vertical px/lane.
__global__ __launch_bounds__(256) void k_main(
    const float* __restrict__ x, const float* __restrict__ ws,
    float* __restrict__ out)
{
    __shared__ _Float16 u_s[128 * 64];  // row=px, 64 f16 K-chunk, XOR-swizzled (16 KB)
    __shared__ _Float16 W_s[128 * 64];  // row=oup (16 KB)
    __shared__ float xs[2][4 * 200];    // dbuf: 4 chans x (10 rows x stride 20)
    __shared__ float bias_s[128];

    int t = threadIdx.x;
    int bid = blockIdx.x;
    int b = bid >> 7, tile = bid & 127;
    int oh0 = (tile >> 3) << 3;         // 16 row-bands of 8
    int ow0 = (tile & 7) << 4;          // 8 col-bands of 16
    if (t < 128) bias_s[t] = ws[WS_BIAS + t];

    const float* xb = x + (size_t)b * C_ * HW_;
    const _Float16* Wh = (const _Float16*)(ws + WS_WH);

    int w = __builtin_amdgcn_readfirstlane(t >> 6);   // wave id (uniform)
    int lane = t & 63, quad = lane >> 4, l15 = lane & 15;
    int col = lane & 15, prow0 = (lane >> 4) << 1;    // u-phase: 2 vertical px

    v4f acc[4][4];
#pragma unroll
    for (int a = 0; a < 4; ++a)
#pragma unroll
        for (int bb = 0; bb < 4; ++bb) acc[a][bb] = (v4f)0.f;

    // ---- stage halo for it=0: wave w stages chan w (10 x 18, stride 20)
    {
        const float* xc = xb + (size_t)w * HW_;
#pragma unroll
        for (int i = 0; i < 3; ++i) {
            int item = lane + i * 64;
            if (item < 180) {
                int r = item / 18, cl = item - r * 18;
                int yy = oh0 + r - 1, xx = ow0 + cl - 1;
                float v = 0.f;
                if (yy >= 0 && yy < 128 && xx >= 0 && xx < 128) v = xc[yy * 128 + xx];
                xs[0][w * 200 + r * 20 + cl] = v;
            }
        }
    }
    __syncthreads();

    int buf = 0;
    for (int it = 0; it < 16; ++it) {
        int c = it * 4 + w;                            // wave-uniform channel

        // ---- issue W-chunk global loads early (consumed after u-phase)
        float4 wld[4];
#pragma unroll
        for (int i = 0; i < 4; ++i) {
            int id = t + i * 256; int oup = id >> 3, kb = id & 7;
            wld[i] = *(const float4*)(Wh + oup * 1024 + it * 64 + kb * 8);
        }

        // ---- u-phase: chan c, 2 vertical px per lane
        const float* xw = &xs[buf][w * 200];
        float nb[12];                                  // rows prow0..+3, cols col..+2
#pragma unroll
        for (int dr = 0; dr < 4; ++dr)
#pragma unroll
            for (int dc = 0; dc < 3; ++dc)
                nb[dr * 3 + dc] = xw[(prow0 + dr) * 20 + col + dc];

        const float* wfp = ws + WS_WFOLD + c * 81;     // uniform -> s_load
        const float* shp = ws + WS_SHIFT + c * 9;
        float4 g4 = *(const float4*)(ws + WS_GATE + (((b << 6) + c) << 2));

        int p0 = prow0 * 16 + col;                     // px of first of the pair
        int swzA0 = ((2 * w) ^ (p0 & 7)) << 3;         // elem offsets (f16 units)
        int swzA1 = ((2 * w) ^ ((p0 + 16) & 7)) << 3;
        int swzB0 = ((2 * w + 1) ^ (p0 & 7)) << 3;
        int swzB1 = ((2 * w + 1) ^ ((p0 + 16) & 7)) << 3;

#pragma unroll 1
        for (int jp = 0; jp < 4; ++jp) {               // j pair {2jp, 2jp+1}
            float wl[18];
#pragma unroll
            for (int i = 0; i < 18; ++i) wl[i] = wfp[jp * 18 + i];
            float s0 = shp[jp * 2], s1v = shp[jp * 2 + 1];
#pragma unroll
            for (int px = 0; px < 2; ++px) {
                float a0 = s0, a1 = s1v;
#pragma unroll
                for (int k = 0; k < 9; ++k) {
                    float xv = nb[(px + k / 3) * 3 + (k % 3)];
                    a0 = fmaf(wl[k], xv, a0);
                    a1 = fmaf(wl[9 + k], xv, a1);
                }
                float v0 = fmaxf(a0, 0.f), v1 = fmaxf(a1, 0.f);
                float e0 = __builtin_amdgcn_exp2f(fmaf(g4.z, v0, g4.w));
                float e1 = __builtin_amdgcn_exp2f(fmaf(g4.z, v1, g4.w));
                float u0 = v0 * fmaf(g4.y, __builtin_amdgcn_rcpf(1.f + e0), g4.x);
                float u1 = v1 * fmaf(g4.y, __builtin_amdgcn_rcpf(1.f + e1), g4.x);
                int base = (p0 + px * 16) * 64 + (px ? swzA1 : swzA0);
                *(fp16x2*)&u_s[base + jp * 2] = __builtin_amdgcn_cvt_pkrtz(u0, u1);
            }
        }
        {   // j = 8 -> odd octet: {u8, 0, 0, 0, 0, 0, 0, 0} as one b128 per px
            float w9[9];
#pragma unroll
            for (int i = 0; i < 9; ++i) w9[i] = wfp[72 + i];
            float s8 = shp[8];
#pragma unroll
            for (int px = 0; px < 2; ++px) {
                float a0 = s8;
#pragma unroll
                for (int k = 0; k < 9; ++k)
                    a0 = fmaf(w9[k], nb[(px + k / 3) * 3 + (k % 3)], a0);
                float v0 = fmaxf(a0, 0.f);
                float e0 = __builtin_amdgcn_exp2f(fmaf(g4.z, v0, g4.w));
                float u8 = v0 * fmaf(g4.y, __builtin_amdgcn_rcpf(1.f + e0), g4.x);
                union { fp16x2 p[4]; float4 f; } z;
                z.p[0] = __builtin_amdgcn_cvt_pkrtz(u8, 0.f);
                z.p[1] = __builtin_amdgcn_cvt_pkrtz(0.f, 0.f);
                z.p[2] = z.p[1]; z.p[3] = z.p[1];
                int base = (p0 + px * 16) * 64 + (px ? swzB1 : swzB0);
                *(float4*)&u_s[base] = z.f;
            }
        }

        // ---- write W chunk to LDS (XOR swizzle), stage halo(it+1)
#pragma unroll
        for (int i = 0; i < 4; ++i) {
            int id = t + i * 256; int oup = id >> 3, kb = id & 7;
            *(float4*)&W_s[oup * 64 + ((kb ^ (oup & 7)) << 3)] = wld[i];
        }
        if (it < 15) {
            const float* xc = xb + (size_t)(it * 4 + 4 + w) * HW_;
#pragma unroll
            for (int i = 0; i < 3; ++i) {
                int item = lane + i * 64;
                if (item < 180) {
                    int r = item / 18, cl = item - r * 18;
                    int yy = oh0 + r - 1, xx = ow0 + cl - 1;
                    float v = 0.f;
                    if (yy >= 0 && yy < 128 && xx >= 0 && xx < 128) v = xc[yy * 128 + xx];
                    xs[buf ^ 1][w * 200 + r * 20 + cl] = v;
                }
            }
        }
        __syncthreads();

        // ---- MFMA: wave w owns oups [(w&1)*64,+64) x px [(w>>1)*64,+64)
#pragma unroll
        for (int ks = 0; ks < 2; ++ks) {
            int kb = ks * 4 + quad;
            v8h A[4], Bf[4];
#pragma unroll
            for (int a = 0; a < 4; ++a) {
                int row = ((w & 1) << 6) + (a << 4) + l15;
                A[a] = *(const v8h*)&W_s[row * 64 + ((kb ^ (row & 7)) << 3)];
            }
#pragma unroll
            for (int bb = 0; bb < 4; ++bb) {
                int row = ((w >> 1) << 6) + (bb << 4) + l15;
                Bf[bb] = *(const v8h*)&u_s[row * 64 + ((kb ^ (row & 7)) << 3)];
            }
#pragma unroll
            for (int a = 0; a < 4; ++a)
#pragma unroll
                for (int bb = 0; bb < 4; ++bb)
                    acc[a][bb] = __builtin_amdgcn_mfma_f32_16x16x32_f16(A[a], Bf[bb], acc[a][bb], 0, 0, 0);
        }
        __syncthreads();
        buf ^= 1;
    }

    // ---- epilogue: bias + SiLU; C/D layout col=lane&15(px), row=quad*4+reg(oup)
    size_t ob = (size_t)b * 128 * HW_;
#pragma unroll
    for (int a = 0; a < 4; ++a) {
#pragma unroll
        for (int r = 0; r < 4; ++r) {
            int oup = ((w & 1) << 6) + (a << 4) + (quad << 2) + r;
            float bo = bias_s[oup];
#pragma unroll
            for (int bb = 0; bb < 4; ++bb) {
                int p2 = ((w >> 1) << 6) + (bb << 4) + l15;
                int py2 = p2 >> 4, px2 = p2 & 15;
                float z = acc[a][bb][r] + bo;
                out[ob + (size_t)oup * HW_ + (oh0 + py2) * W_ + ow0 + px2] = z * sigmf(z);
            }
        }
    }
}

extern "C" void kernel_launch(void* const* d_in, const int* in_sizes, int n_in,
                              void* d_out, int out_size, void* d_ws, size_t ws_size,
                              hipStream_t stream)
{
    const float* x      = (const float*)d_in[0];
    const float* gen_w  = (const float*)d_in[1];
    const float* gg     = (const float*)d_in[2];
    const float* gb     = (const float*)d_in[3];
    const float* gm     = (const float*)d_in[4];
    const float* gv     = (const float*)d_in[5];
    const float* gnw    = (const float*)d_in[6];
    const float* gnb    = (const float*)d_in[7];
    const float* cwt    = (const float*)d_in[8];
    const float* cbs    = (const float*)d_in[9];
    const float* swt    = (const float*)d_in[10];
    const float* sbs    = (const float*)d_in[11];
    const float* wadd   = (const float*)d_in[12];
    const float* conv_w = (const float*)d_in[13];
    const float* cg2    = (const float*)d_in[14];
    const float* cb2    = (const float*)d_in[15];
    const float* cm2    = (const float*)d_in[16];
    const float* cv2    = (const float*)d_in[17];
    float* ws  = (float*)d_ws;
    float* out = (float*)d_out;

    k_fold<<<535, 256, 0, stream>>>(gen_w, gg, gb, gm, gv, conv_w, cg2, cb2, cm2, cv2, ws);
    k_stats<<<2048, 256, 0, stream>>>(x, ws, ws + WS_PART);
    k_gate<<<2, 256, 0, stream>>>(ws + WS_PART, cwt, cbs, swt, sbs, gnw, gnb, wadd,
                                  (float4*)(ws + WS_GATE));
    k_main<<<1024, 256, 0, stream>>>(x, ws, out);
}